// Round 19
// baseline (87.708 us; speedup 1.0000x reference)
//
#include <hip/hip_runtime.h>
#include <hip/hip_bf16.h>
#include <math.h>

// Problem constants
// B=16, T=4096, E=384, H=64; M = B*T = 65536
// Y layout: [m][0..127] = K|Q (bf16, stride 128). Q is pre-scaled by
// zsc = E^-0.5*log2(e) at k_pack (folded into Wq). V goes straight to VT.

typedef __attribute__((ext_vector_type(4))) float f32x4;
typedef __attribute__((ext_vector_type(8))) __bf16 bf16x8;

#define DEVI static __device__ __forceinline__

DEVI unsigned short f2bf(float f) {
  union { float f; unsigned int u; } x; x.f = f;
  unsigned int r = x.u + 0x7fffu + ((x.u >> 16) & 1u);
  return (unsigned short)(r >> 16);
}

DEVI float bf2f(unsigned int u) {
  union { unsigned int u; float f; } x; x.u = u << 16;
  return x.f;
}

DEVI unsigned int cvtpk_bf16(float lo, float hi) {
  unsigned int r;
  asm("v_cvt_pk_bf16_f32 %0, %1, %2" : "=v"(r) : "v"(lo), "v"(hi));
  return r;
}

DEVI f32x4 mfma16(bf16x8 a, bf16x8 b, f32x4 c) {
  return __builtin_amdgcn_mfma_f32_16x16x32_bf16(a, b, c, 0, 0, 0);
}

// 64-elem-wide LDS rows (128 B): XOR-swizzle at 16-B granule with row&7.
DEVI bf16x8 lds_frag(const unsigned short* buf, int row, int gran) {
  return *(const bf16x8*)(buf + row * 64 + ((gran ^ (row & 7)) << 3));
}

// async 16-B global -> LDS DMA (linear dest; swizzle applied on the GLOBAL src)
DEVI void gl_lds16(const unsigned short* g, unsigned short* l) {
  __builtin_amdgcn_global_load_lds(
      (const __attribute__((address_space(1))) unsigned int*)g,
      (__attribute__((address_space(3))) unsigned int*)l, 16, 0, 0);
}

// ---------------------------------------------------------------------------
// k_pack: WT[n][k] bf16, n in [0,192) = concat(Wk,Wq,Wv) columns, k in [0,384)
// Wq columns (n in [64,128)) are pre-scaled by zsc.
// ---------------------------------------------------------------------------
__global__ __launch_bounds__(256) void k_pack(const float* __restrict__ Wk,
                                              const float* __restrict__ Wq,
                                              const float* __restrict__ Wv,
                                              unsigned short* __restrict__ WT) {
  int idx = blockIdx.x * 256 + threadIdx.x;
  if (idx >= 192 * 384) return;
  int n = idx / 384, k = idx - n * 384;
  const float* W = (n < 64) ? Wk : ((n < 128) ? Wq : Wv);
  float val = W[k * 64 + (n & 63)];
  if (n >= 64 && n < 128) val *= 0.073622223f;  // 384^-0.5 * log2(e)
  WT[idx] = f2bf(val);
}

// ---------------------------------------------------------------------------
// k_proj: [K|Q|V] = x @ [Wk|Wq|Wv];  K|Q -> Y[m][128], V -> VT[b][d][t] (fused
// transpose store, packed uint2). BM=64, BN=192, BK=64; 4 waves 2x2.
// Stage-A fp32->bf16 via v_cvt_pk_bf16_f32.
// ---------------------------------------------------------------------------
__global__ __launch_bounds__(256, 4) void k_proj(const float* __restrict__ x,
                                                 const unsigned short* __restrict__ WT,
                                                 unsigned short* __restrict__ Y,
                                                 unsigned short* __restrict__ VT) {
  __shared__ __align__(16) unsigned short As[64 * 64];
  __shared__ __align__(16) unsigned short Bs[192 * 64];
  const int tid = threadIdx.x;
  const int lane = tid & 63, wid = tid >> 6;
  const int q = lane & 15, g = lane >> 4;
  const int wm = wid >> 1, wn = wid & 1;
  const int m0 = blockIdx.x * 64;

  f32x4 acc[2][6];
#pragma unroll
  for (int mt = 0; mt < 2; ++mt)
#pragma unroll
    for (int nt = 0; nt < 6; ++nt) acc[mt][nt] = f32x4{0.f, 0.f, 0.f, 0.f};

  const int ar = tid >> 2, ap = tid & 3;  // A staging: row, 16-float quarter

  for (int ks = 0; ks < 6; ++ks) {
    // stage A: x fp32 -> bf16 (cvt_pk), 64 rows x 64 k
    const float4* xp = (const float4*)(x + (size_t)(m0 + ar) * 384 + ks * 64 + ap * 16);
#pragma unroll
    for (int cc = 0; cc < 2; ++cc) {
      float4 f0 = xp[cc * 2], f1 = xp[cc * 2 + 1];
      uint4 v;
      v.x = cvtpk_bf16(f0.x, f0.y);
      v.y = cvtpk_bf16(f0.z, f0.w);
      v.z = cvtpk_bf16(f1.x, f1.y);
      v.w = cvtpk_bf16(f1.z, f1.w);
      int gran = ap * 2 + cc;
      *(uint4*)(As + ar * 64 + ((gran ^ (ar & 7)) << 3)) = v;
    }
    // stage B: WT rows (n-major), 192 rows x 64 k
#pragma unroll
    for (int i = 0; i < 6; ++i) {
      int c = tid + 256 * i;
      int row = c >> 3, gr = c & 7;
      uint4 w = *(const uint4*)(WT + (size_t)row * 384 + ks * 64 + gr * 8);
      *(uint4*)(Bs + row * 64 + ((gr ^ (row & 7)) << 3)) = w;
    }
    __syncthreads();
#pragma unroll
    for (int kk = 0; kk < 2; ++kk) {
      bf16x8 af[2], bfv[6];
#pragma unroll
      for (int mt = 0; mt < 2; ++mt) af[mt] = lds_frag(As, wm * 32 + mt * 16 + q, kk * 4 + g);
#pragma unroll
      for (int nt = 0; nt < 6; ++nt) bfv[nt] = lds_frag(Bs, wn * 96 + nt * 16 + q, kk * 4 + g);
#pragma unroll
      for (int mt = 0; mt < 2; ++mt)
#pragma unroll
        for (int nt = 0; nt < 6; ++nt) acc[mt][nt] = mfma16(af[mt], bfv[nt], acc[mt][nt]);
    }
    __syncthreads();
  }
  // epilogue: C/D layout col=lane&15 (n), row=4*(lane>>4)+j (m).
#pragma unroll
  for (int mt = 0; mt < 2; ++mt) {
    const int mrow = m0 + wm * 32 + mt * 16 + g * 4;
#pragma unroll
    for (int nt = 0; nt < 6; ++nt) {
      const int ncol = wn * 96 + nt * 16 + q;
      if (wn == 1 && nt >= 2) {
        const int d = (nt - 2) * 16 + q;
        const int bb = mrow >> 12, t = mrow & 4095;
        uint2 pv;
        pv.x = cvtpk_bf16(acc[mt][nt][0], acc[mt][nt][1]);
        pv.y = cvtpk_bf16(acc[mt][nt][2], acc[mt][nt][3]);
        *(uint2*)(VT + (size_t)(bb * 64 + d) * 4096 + t) = pv;
      } else {
        size_t base = (size_t)mrow * 128 + ncol;
#pragma unroll
        for (int j = 0; j < 4; ++j) Y[base + (size_t)j * 128] = f2bf(acc[mt][nt][j]);
      }
    }
  }
}

// ---------------------------------------------------------------------------
// k_attn: flash attention, causal. R16 internals unchanged: 8 waves,
// QBLOCK=128, KVBLK=64, kv-parity split, 32 q-rows/wave (qh=0,1), kv-permuted
// K staging -> register-resident P, 4-slot ring, one barrier per 2 tiles,
// max-free softmax, in-block parity merge, partials to workspace + k_red.
// R19 single mechanism: SEQUENTIAL JOB PAIRING (R3-proven pattern). 512
// blocks, each runs two jobs back-to-back: phase A = (i=31-(s>>1), h=s&1),
// phase B = (31-iA, hA^1). Pair lengths sum to 16-17 iterations for EVERY
// block; all 512 blocks co-resident (2/CU) -> zero scheduler refill, flat
// occupancy, makespan ~17 vs R16's ~19 (two-layer refill tail).
// ---------------------------------------------------------------------------
__global__ __launch_bounds__(512, 4) void k_attn(const unsigned short* __restrict__ Y,
                                                 const unsigned short* __restrict__ VT,
                                                 unsigned short* __restrict__ PO,
                                                 float* __restrict__ PL) {
  __shared__ __align__(16) unsigned short Ks[4][64 * 64];
  __shared__ __align__(16) unsigned short Vs[4][64 * 64];

  // id: [2:0]=xcd, [3]=batch half, [8:4]=pair slot s 0..31.
  const int id = blockIdx.x;
  const int xcd = id & 7;
  const int b = xcd * 2 + ((id >> 3) & 1);
  const int s = id >> 4;  // 0..31

  const int tid = threadIdx.x;
  const int lane = tid & 63, wid = tid >> 6;
  const int p = wid >> 2;   // KV parity group
  const int w4 = wid & 3;   // wave within group
  const int q = lane & 15, g = lane >> 4;

  const unsigned short* Yb = Y + (size_t)b * 4096 * 128;
  const unsigned short* Vb = VT + (size_t)b * 64 * 4096;

  // stage tile at KV0 into ring slot S. K rows are staged PERMUTED so that
  // LDS row L holds global kv row kvperm(L); V rows are d-indexed (linear).
#define STAGE(S, KV0)                                                           \
  {                                                                             \
    int r = tid >> 3, grs = (tid & 7) ^ (r & 7);                                \
    int kp = (r & 32) | ((r & 12) << 1) | ((r & 16) >> 2) | (r & 3);            \
    gl_lds16(Yb + (size_t)((KV0) + kp) * 128 + grs * 8, Ks[S] + tid * 8);       \
    gl_lds16(Vb + (size_t)r * 4096 + (KV0) + grs * 8, Vs[S] + tid * 8);         \
  }

  for (int phase = 0; phase < 2; ++phase) {
    // job parameters for this phase (pairing: B is the complement of A)
    const int i = phase ? (s >> 1) : (31 - (s >> 1));
    const int h = phase ? ((s & 1) ^ 1) : (s & 1);
    const int nIt = i + 1, nH0 = (nIt + 1) >> 1;
    const int itBeg = h ? nH0 : 0;
    const int itEnd = h ? nIt : nH0;
    const int q0 = i * 128;
    const int tEnd = 2 * itEnd;  // exclusive tile bound for this job

    // Q fragments for both q-halves (already scaled by zsc via k_pack)
    bf16x8 qf[2][2];
#pragma unroll
    for (int qh = 0; qh < 2; ++qh) {
      const unsigned short* qp = Yb + (size_t)(q0 + w4 * 32 + qh * 16 + q) * 128 + 64;
      qf[qh][0] = *(const bf16x8*)(qp + g * 8);
      qf[qh][1] = *(const bf16x8*)(qp + 32 + g * 8);
    }

    f32x4 accO[2][4];
#pragma unroll
    for (int qh = 0; qh < 2; ++qh)
#pragma unroll
      for (int dt = 0; dt < 4; ++dt) accO[qh][dt] = f32x4{0.f, 0.f, 0.f, 0.f};
    float lsum[2] = {0.f, 0.f};

    // tiles this wave needs: waves 0,1 of a group stop one tile earlier
    const int mytiles = 2 * i + 1 + (w4 >> 1);

    if (itBeg < itEnd) {  // block-uniform: some jobs (i=0 upper half) are empty
      {
        const int tb = 2 * itBeg;
        STAGE(tb & 3, tb * 64)
        STAGE((tb + 1) & 3, (tb + 1) * 64)
      }
      __syncthreads();

      for (int it = itBeg; it < itEnd; ++it) {
        const int kt = 2 * it + p;
        const int t2 = 2 * it + 2, t3 = 2 * it + 3;
        if (t2 < tEnd) STAGE(t2 & 3, t2 * 64)
        if (t3 < tEnd) STAGE(t3 & 3, t3 * 64)

        if (kt < mytiles) {
          const int kv0 = kt * 64;
          const unsigned short* Kc = Ks[kt & 3];
          const unsigned short* Vc = Vs[kt & 3];

          // ---- S^T = K . Q^T for both q-halves (K fragments read once).
          // Permuted staging: accS[qh][t][j] holds kv offset
          // (t>>1)*32 + g*8 + (t&1)*4 + j -- exactly PV's B-fragment order.
          bf16x8 ka0[4], ka1[4];
#pragma unroll
          for (int t = 0; t < 4; ++t) {
            ka0[t] = lds_frag(Kc, t * 16 + q, g);
            ka1[t] = lds_frag(Kc, t * 16 + q, 4 + g);
          }
          f32x4 accS[2][4];
          __builtin_amdgcn_s_setprio(1);
#pragma unroll
          for (int qh = 0; qh < 2; ++qh)
#pragma unroll
            for (int t = 0; t < 4; ++t) {
              f32x4 z = f32x4{0.f, 0.f, 0.f, 0.f};
              z = mfma16(ka0[t], qf[qh][0], z);
              z = mfma16(ka1[t], qf[qh][1], z);
              accS[qh][t] = z;
            }
          __builtin_amdgcn_s_setprio(0);

          // ---- max-free softmax per q-half; P assembled IN-REGISTER ----
          const bool dmw = (kv0 + 63 >= q0 + w4 * 32);  // diagonal tile
          bf16x8 bp[2][2];
#pragma unroll
          for (int qh = 0; qh < 2; ++qh) {
            if (dmw) {
              const int qrow = q0 + w4 * 32 + qh * 16 + q;
#pragma unroll
              for (int t = 0; t < 4; ++t)
#pragma unroll
                for (int j = 0; j < 4; ++j) {
                  const int kvl = ((t >> 1) << 5) + (g << 3) + ((t & 1) << 2) + j;
                  if (kv0 + kvl > qrow) accS[qh][t][j] = -INFINITY;
                }
            }
            float pp[4][4];
            float ps0 = 0.f, ps1 = 0.f;
#pragma unroll
            for (int t = 0; t < 4; ++t) {
              pp[t][0] = __builtin_amdgcn_exp2f(accS[qh][t][0]);
              pp[t][1] = __builtin_amdgcn_exp2f(accS[qh][t][1]);
              pp[t][2] = __builtin_amdgcn_exp2f(accS[qh][t][2]);
              pp[t][3] = __builtin_amdgcn_exp2f(accS[qh][t][3]);
              ps0 += pp[t][0] + pp[t][1];
              ps1 += pp[t][2] + pp[t][3];
            }
            lsum[qh] += ps0 + ps1;
            uint4 u0, u1;
            u0.x = cvtpk_bf16(pp[0][0], pp[0][1]);
            u0.y = cvtpk_bf16(pp[0][2], pp[0][3]);
            u0.z = cvtpk_bf16(pp[1][0], pp[1][1]);
            u0.w = cvtpk_bf16(pp[1][2], pp[1][3]);
            u1.x = cvtpk_bf16(pp[2][0], pp[2][1]);
            u1.y = cvtpk_bf16(pp[2][2], pp[2][3]);
            u1.z = cvtpk_bf16(pp[3][0], pp[3][1]);
            u1.w = cvtpk_bf16(pp[3][2], pp[3][3]);
            bp[qh][0] = __builtin_bit_cast(bf16x8, u0);
            bp[qh][1] = __builtin_bit_cast(bf16x8, u1);
          }

          // ---- O^T += V^T . P^T (V fragments read once, both q-halves) ----
          __builtin_amdgcn_s_setprio(1);
#pragma unroll
          for (int dt = 0; dt < 4; ++dt) {
            bf16x8 av0 = lds_frag(Vc, dt * 16 + q, g);
            bf16x8 av1 = lds_frag(Vc, dt * 16 + q, 4 + g);
#pragma unroll
            for (int qh = 0; qh < 2; ++qh) {
              accO[qh][dt] = mfma16(av0, bp[qh][0], accO[qh][dt]);
              accO[qh][dt] = mfma16(av1, bp[qh][1], accO[qh][dt]);
            }
          }
          __builtin_amdgcn_s_setprio(0);
        }

        __syncthreads();  // drains prefetch DMAs; frees this iteration's slots
      }
    }

    // group-local full row sums
#pragma unroll
    for (int qh = 0; qh < 2; ++qh) {
      lsum[qh] += __shfl_xor(lsum[qh], 16);
      lsum[qh] += __shfl_xor(lsum[qh], 32);
    }

    // ---- in-block parity merge via LDS scratch (ring is idle) ----
    float* scrO = (float*)Ks;
    float* scrL = (float*)Vs;
    const int si = (w4 * 64 + lane) * 2;
    if (p == 1) {
#pragma unroll
      for (int qh = 0; qh < 2; ++qh) {
        float* so = scrO + (si + qh) * 16;
#pragma unroll
        for (int dt = 0; dt < 4; ++dt) *(float4*)(so + dt * 4) = *(float4*)&accO[qh][dt];
        scrL[si + qh] = lsum[qh];
      }
    }
    __syncthreads();
    if (p == 0) {
      // write UNNORMALIZED partials -- O as bf16 (packed), l as f32
      const int jobj = (b << 5) + i;  // 0..511
      unsigned short* PO_ = PO + ((size_t)(jobj * 2 + h)) * 8192;
      float* PL_ = PL + (jobj * 2 + h) * 128;
#pragma unroll
      for (int qh = 0; qh < 2; ++qh) {
        const float* so = scrO + (si + qh) * 16;
        const float lt = lsum[qh] + scrL[si + qh];
        const int row = w4 * 32 + qh * 16 + q;
        if (g == 0) PL_[row] = lt;
#pragma unroll
        for (int dt = 0; dt < 4; ++dt) {
          float4 ob = *(const float4*)(so + dt * 4);
          uint2 pv;
          pv.x = cvtpk_bf16(accO[qh][dt][0] + ob.x, accO[qh][dt][1] + ob.y);
          pv.y = cvtpk_bf16(accO[qh][dt][2] + ob.z, accO[qh][dt][3] + ob.w);
          *(uint2*)(PO_ + row * 64 + dt * 16 + g * 4) = pv;
        }
      }
    }
    if (phase == 0) __syncthreads();  // scratch reads done before phase B stages
  }
#undef STAGE
}

// ---------------------------------------------------------------------------
// k_red: merge split-K partials. O = (O0 + O1) / (l0 + l1).
// 32 B per thread (uint4 per half, 2x float4 out).
// 512 jobs x 128 rows x 8 d-octs = 524288 threads -> 2048 blocks.
// ---------------------------------------------------------------------------
__global__ __launch_bounds__(256) void k_red(const unsigned short* __restrict__ PO,
                                             const float* __restrict__ PL,
                                             float* __restrict__ out) {
  const int idx = blockIdx.x * 256 + threadIdx.x;
  const int dv = idx & 7;            // 8-elem d-oct
  const int row = (idx >> 3) & 127;
  const int j = idx >> 10;           // 0..511 = b*32 + i
  const int b = j >> 5, i = j & 31;

  const unsigned short* a0 = PO + ((size_t)(j * 2)) * 8192 + row * 64 + dv * 8;
  const uint4 u0 = *(const uint4*)a0;
  const uint4 u1 = *(const uint4*)(a0 + 8192);
  const float rl = 1.0f / (PL[(j * 2) * 128 + row] + PL[(j * 2 + 1) * 128 + row]);

  float* op = out + ((size_t)(b * 4096 + i * 128 + row)) * 64 + dv * 8;
  float4 o0, o1;
  o0.x = (bf2f(u0.x & 0xffffu) + bf2f(u1.x & 0xffffu)) * rl;
  o0.y = (bf2f(u0.x >> 16) + bf2f(u1.x >> 16)) * rl;
  o0.z = (bf2f(u0.y & 0xffffu) + bf2f(u1.y & 0xffffu)) * rl;
  o0.w = (bf2f(u0.y >> 16) + bf2f(u1.y >> 16)) * rl;
  o1.x = (bf2f(u0.z & 0xffffu) + bf2f(u1.z & 0xffffu)) * rl;
  o1.y = (bf2f(u0.z >> 16) + bf2f(u1.z >> 16)) * rl;
  o1.z = (bf2f(u0.w & 0xffffu) + bf2f(u1.w & 0xffffu)) * rl;
  o1.w = (bf2f(u0.w >> 16) + bf2f(u1.w >> 16)) * rl;
  *(float4*)op = o0;
  *(float4*)(op + 4) = o1;
}

// ---------------------------------------------------------------------------
extern "C" void kernel_launch(void* const* d_in, const int* in_sizes, int n_in,
                              void* d_out, int out_size, void* d_ws, size_t ws_size,
                              hipStream_t stream) {
  const float* x  = (const float*)d_in[0];
  const float* Wk = (const float*)d_in[1];
  const float* Wq = (const float*)d_in[2];
  const float* Wv = (const float*)d_in[3];
  float* out = (float*)d_out;

  // workspace (ushorts): WT 73728 | Y 8388608 | VT 4194304 | PO 8388608 |
  // PL 131072 f32 (262144 ushort-equiv). Total ~42.6 MB.
  unsigned short* WT = (unsigned short*)d_ws;
  unsigned short* Y  = WT + 73728;
  unsigned short* VT = Y + 8388608;
  unsigned short* PO = VT + 4194304;
  float*          PL = (float*)(PO + 8388608);

  hipLaunchKernelGGL(k_pack, dim3(288), dim3(256), 0, stream, Wk, Wq, Wv, WT);
  hipLaunchKernelGGL(k_proj, dim3(1024), dim3(256), 0, stream, x, WT, Y, VT);
  hipLaunchKernelGGL(k_attn, dim3(512), dim3(512), 0, stream, Y, VT, PO, PL);
  hipLaunchKernelGGL(k_red, dim3(2048), dim3(256), 0, stream, PO, PL, out);
}

// Round 20
// 84.913 us; speedup vs baseline: 1.0329x; 1.0329x over previous
//
#include <hip/hip_runtime.h>
#include <hip/hip_bf16.h>
#include <math.h>

// Problem constants
// B=16, T=4096, E=384, H=64; M = B*T = 65536
// Y layout: [m][0..127] = K|Q (bf16, stride 128). Q is pre-scaled by
// zsc = E^-0.5*log2(e) at k_pack (folded into Wq). V goes straight to VT.

typedef __attribute__((ext_vector_type(4))) float f32x4;
typedef __attribute__((ext_vector_type(8))) __bf16 bf16x8;

#define DEVI static __device__ __forceinline__

DEVI unsigned short f2bf(float f) {
  union { float f; unsigned int u; } x; x.f = f;
  unsigned int r = x.u + 0x7fffu + ((x.u >> 16) & 1u);
  return (unsigned short)(r >> 16);
}

DEVI float bf2f(unsigned int u) {
  union { unsigned int u; float f; } x; x.u = u << 16;
  return x.f;
}

DEVI unsigned int cvtpk_bf16(float lo, float hi) {
  unsigned int r;
  asm("v_cvt_pk_bf16_f32 %0, %1, %2" : "=v"(r) : "v"(lo), "v"(hi));
  return r;
}

DEVI f32x4 mfma16(bf16x8 a, bf16x8 b, f32x4 c) {
  return __builtin_amdgcn_mfma_f32_16x16x32_bf16(a, b, c, 0, 0, 0);
}

// 64-elem-wide LDS rows (128 B): XOR-swizzle at 16-B granule with row&7.
DEVI bf16x8 lds_frag(const unsigned short* buf, int row, int gran) {
  return *(const bf16x8*)(buf + row * 64 + ((gran ^ (row & 7)) << 3));
}

// async 16-B global -> LDS DMA (linear dest; swizzle applied on the GLOBAL src)
DEVI void gl_lds16(const unsigned short* g, unsigned short* l) {
  __builtin_amdgcn_global_load_lds(
      (const __attribute__((address_space(1))) unsigned int*)g,
      (__attribute__((address_space(3))) unsigned int*)l, 16, 0, 0);
}

// ---------------------------------------------------------------------------
// k_pack: WT[n][k] bf16, n in [0,192) = concat(Wk,Wq,Wv) columns, k in [0,384)
// Wq columns (n in [64,128)) are pre-scaled by zsc.
// ---------------------------------------------------------------------------
__global__ __launch_bounds__(256) void k_pack(const float* __restrict__ Wk,
                                              const float* __restrict__ Wq,
                                              const float* __restrict__ Wv,
                                              unsigned short* __restrict__ WT) {
  int idx = blockIdx.x * 256 + threadIdx.x;
  if (idx >= 192 * 384) return;
  int n = idx / 384, k = idx - n * 384;
  const float* W = (n < 64) ? Wk : ((n < 128) ? Wq : Wv);
  float val = W[k * 64 + (n & 63)];
  if (n >= 64 && n < 128) val *= 0.073622223f;  // 384^-0.5 * log2(e)
  WT[idx] = f2bf(val);
}

// ---------------------------------------------------------------------------
// k_proj: [K|Q|V] = x @ [Wk|Wq|Wv];  K|Q -> Y[m][128], V -> VT[b][d][t] (fused
// transpose store, packed uint2). BM=64, BN=192, BK=64; 4 waves 2x2.
// Stage-A fp32->bf16 via v_cvt_pk_bf16_f32.
// ---------------------------------------------------------------------------
__global__ __launch_bounds__(256, 4) void k_proj(const float* __restrict__ x,
                                                 const unsigned short* __restrict__ WT,
                                                 unsigned short* __restrict__ Y,
                                                 unsigned short* __restrict__ VT) {
  __shared__ __align__(16) unsigned short As[64 * 64];
  __shared__ __align__(16) unsigned short Bs[192 * 64];
  const int tid = threadIdx.x;
  const int lane = tid & 63, wid = tid >> 6;
  const int q = lane & 15, g = lane >> 4;
  const int wm = wid >> 1, wn = wid & 1;
  const int m0 = blockIdx.x * 64;

  f32x4 acc[2][6];
#pragma unroll
  for (int mt = 0; mt < 2; ++mt)
#pragma unroll
    for (int nt = 0; nt < 6; ++nt) acc[mt][nt] = f32x4{0.f, 0.f, 0.f, 0.f};

  const int ar = tid >> 2, ap = tid & 3;  // A staging: row, 16-float quarter

  for (int ks = 0; ks < 6; ++ks) {
    // stage A: x fp32 -> bf16 (cvt_pk), 64 rows x 64 k
    const float4* xp = (const float4*)(x + (size_t)(m0 + ar) * 384 + ks * 64 + ap * 16);
#pragma unroll
    for (int cc = 0; cc < 2; ++cc) {
      float4 f0 = xp[cc * 2], f1 = xp[cc * 2 + 1];
      uint4 v;
      v.x = cvtpk_bf16(f0.x, f0.y);
      v.y = cvtpk_bf16(f0.z, f0.w);
      v.z = cvtpk_bf16(f1.x, f1.y);
      v.w = cvtpk_bf16(f1.z, f1.w);
      int gran = ap * 2 + cc;
      *(uint4*)(As + ar * 64 + ((gran ^ (ar & 7)) << 3)) = v;
    }
    // stage B: WT rows (n-major), 192 rows x 64 k
#pragma unroll
    for (int i = 0; i < 6; ++i) {
      int c = tid + 256 * i;
      int row = c >> 3, gr = c & 7;
      uint4 w = *(const uint4*)(WT + (size_t)row * 384 + ks * 64 + gr * 8);
      *(uint4*)(Bs + row * 64 + ((gr ^ (row & 7)) << 3)) = w;
    }
    __syncthreads();
#pragma unroll
    for (int kk = 0; kk < 2; ++kk) {
      bf16x8 af[2], bfv[6];
#pragma unroll
      for (int mt = 0; mt < 2; ++mt) af[mt] = lds_frag(As, wm * 32 + mt * 16 + q, kk * 4 + g);
#pragma unroll
      for (int nt = 0; nt < 6; ++nt) bfv[nt] = lds_frag(Bs, wn * 96 + nt * 16 + q, kk * 4 + g);
#pragma unroll
      for (int mt = 0; mt < 2; ++mt)
#pragma unroll
        for (int nt = 0; nt < 6; ++nt) acc[mt][nt] = mfma16(af[mt], bfv[nt], acc[mt][nt]);
    }
    __syncthreads();
  }
  // epilogue: C/D layout col=lane&15 (n), row=4*(lane>>4)+j (m).
#pragma unroll
  for (int mt = 0; mt < 2; ++mt) {
    const int mrow = m0 + wm * 32 + mt * 16 + g * 4;
#pragma unroll
    for (int nt = 0; nt < 6; ++nt) {
      const int ncol = wn * 96 + nt * 16 + q;
      if (wn == 1 && nt >= 2) {
        const int d = (nt - 2) * 16 + q;
        const int bb = mrow >> 12, t = mrow & 4095;
        uint2 pv;
        pv.x = cvtpk_bf16(acc[mt][nt][0], acc[mt][nt][1]);
        pv.y = cvtpk_bf16(acc[mt][nt][2], acc[mt][nt][3]);
        *(uint2*)(VT + (size_t)(bb * 64 + d) * 4096 + t) = pv;
      } else {
        size_t base = (size_t)mrow * 128 + ncol;
#pragma unroll
        for (int j = 0; j < 4; ++j) Y[base + (size_t)j * 128] = f2bf(acc[mt][nt][j]);
      }
    }
  }
}

// ---------------------------------------------------------------------------
// k_attn: flash attention, causal. Best-measured structure (R16/R18, total
// ~84.6-85.0us): 8 waves, QBLOCK=128, KVBLK=64, kv-parity split, 32 q-rows
// per wave (qh=0,1), kv-permuted K staging -> register-resident P, 4-slot
// ring, one barrier per 2 tiles, max-free softmax, in-block parity merge,
// uniform 2-way kv split + LPT order, partials to workspace + separate k_red.
// (R19's sequential pairing regressed -- hardware refill beats static
// pairing; R17's atomic merge regressed -- L2 invalidation; both dropped.)
// ---------------------------------------------------------------------------
__global__ __launch_bounds__(512, 4) void k_attn(const unsigned short* __restrict__ Y,
                                                 const unsigned short* __restrict__ VT,
                                                 unsigned short* __restrict__ PO,
                                                 float* __restrict__ PL) {
  __shared__ __align__(16) unsigned short Ks[4][64 * 64];
  __shared__ __align__(16) unsigned short Vs[4][64 * 64];

  // id: [2:0]=xcd, [3]=batch half, [9:4]=job idx 0..63 (length-descending).
  const int id = blockIdx.x;
  const int xcd = id & 7;
  const int b = xcd * 2 + ((id >> 3) & 1);
  const int idx = id >> 4;
  const int i = 31 - (idx >> 1);  // q-tile index, big first (LPT)
  const int h = idx & 1;          // kv half
  const int nIt = i + 1, nH0 = (nIt + 1) >> 1;
  const int itBeg = h ? nH0 : 0;
  const int itEnd = h ? nIt : nH0;
  const int q0 = i * 128;
  const int tEnd = 2 * itEnd;  // exclusive tile bound for this block

  const int tid = threadIdx.x;
  const int lane = tid & 63, wid = tid >> 6;
  const int p = wid >> 2;   // KV parity group
  const int w4 = wid & 3;   // wave within group
  const int q = lane & 15, g = lane >> 4;

  const unsigned short* Yb = Y + (size_t)b * 4096 * 128;
  const unsigned short* Vb = VT + (size_t)b * 64 * 4096;

  // stage tile at KV0 into ring slot S. K rows are staged PERMUTED so that
  // LDS row L holds global kv row kvperm(L); V rows are d-indexed (linear).
#define STAGE(S, KV0)                                                           \
  {                                                                             \
    int r = tid >> 3, grs = (tid & 7) ^ (r & 7);                                \
    int kp = (r & 32) | ((r & 12) << 1) | ((r & 16) >> 2) | (r & 3);            \
    gl_lds16(Yb + (size_t)((KV0) + kp) * 128 + grs * 8, Ks[S] + tid * 8);       \
    gl_lds16(Vb + (size_t)r * 4096 + (KV0) + grs * 8, Vs[S] + tid * 8);         \
  }

  {
    const int tb = 2 * itBeg;
    STAGE(tb & 3, tb * 64)
    STAGE((tb + 1) & 3, (tb + 1) * 64)
  }
  __syncthreads();

  // Q fragments for both q-halves (already scaled by zsc via k_pack)
  bf16x8 qf[2][2];
#pragma unroll
  for (int qh = 0; qh < 2; ++qh) {
    const unsigned short* qp = Yb + (size_t)(q0 + w4 * 32 + qh * 16 + q) * 128 + 64;
    qf[qh][0] = *(const bf16x8*)(qp + g * 8);
    qf[qh][1] = *(const bf16x8*)(qp + 32 + g * 8);
  }

  f32x4 accO[2][4];
#pragma unroll
  for (int qh = 0; qh < 2; ++qh)
#pragma unroll
    for (int dt = 0; dt < 4; ++dt) accO[qh][dt] = f32x4{0.f, 0.f, 0.f, 0.f};
  float lsum[2] = {0.f, 0.f};

  // tiles this wave actually needs: waves 0,1 of a group stop one tile earlier
  const int mytiles = 2 * i + 1 + (w4 >> 1);

  for (int it = itBeg; it < itEnd; ++it) {
    const int kt = 2 * it + p;
    const int t2 = 2 * it + 2, t3 = 2 * it + 3;
    if (t2 < tEnd) STAGE(t2 & 3, t2 * 64)
    if (t3 < tEnd) STAGE(t3 & 3, t3 * 64)

    if (kt < mytiles) {
      const int kv0 = kt * 64;
      const unsigned short* Kc = Ks[kt & 3];
      const unsigned short* Vc = Vs[kt & 3];

      // ---- S^T = K . Q^T for both q-halves (K fragments read once).
      // Permuted staging: accS[qh][t][j] holds kv offset
      // (t>>1)*32 + g*8 + (t&1)*4 + j -- exactly PV's B-fragment order.
      bf16x8 ka0[4], ka1[4];
#pragma unroll
      for (int t = 0; t < 4; ++t) {
        ka0[t] = lds_frag(Kc, t * 16 + q, g);
        ka1[t] = lds_frag(Kc, t * 16 + q, 4 + g);
      }
      f32x4 accS[2][4];
      __builtin_amdgcn_s_setprio(1);
#pragma unroll
      for (int qh = 0; qh < 2; ++qh)
#pragma unroll
        for (int t = 0; t < 4; ++t) {
          f32x4 z = f32x4{0.f, 0.f, 0.f, 0.f};
          z = mfma16(ka0[t], qf[qh][0], z);
          z = mfma16(ka1[t], qf[qh][1], z);
          accS[qh][t] = z;
        }
      __builtin_amdgcn_s_setprio(0);

      // ---- max-free softmax per q-half; P assembled IN-REGISTER ----
      const bool dmw = (kv0 + 63 >= q0 + w4 * 32);  // diagonal tile for this wave
      bf16x8 bp[2][2];
#pragma unroll
      for (int qh = 0; qh < 2; ++qh) {
        if (dmw) {
          const int qrow = q0 + w4 * 32 + qh * 16 + q;
#pragma unroll
          for (int t = 0; t < 4; ++t)
#pragma unroll
            for (int j = 0; j < 4; ++j) {
              const int kvl = ((t >> 1) << 5) + (g << 3) + ((t & 1) << 2) + j;
              if (kv0 + kvl > qrow) accS[qh][t][j] = -INFINITY;
            }
        }
        float pp[4][4];
        float ps0 = 0.f, ps1 = 0.f;
#pragma unroll
        for (int t = 0; t < 4; ++t) {
          pp[t][0] = __builtin_amdgcn_exp2f(accS[qh][t][0]);
          pp[t][1] = __builtin_amdgcn_exp2f(accS[qh][t][1]);
          pp[t][2] = __builtin_amdgcn_exp2f(accS[qh][t][2]);
          pp[t][3] = __builtin_amdgcn_exp2f(accS[qh][t][3]);
          ps0 += pp[t][0] + pp[t][1];
          ps1 += pp[t][2] + pp[t][3];
        }
        lsum[qh] += ps0 + ps1;
        uint4 u0, u1;
        u0.x = cvtpk_bf16(pp[0][0], pp[0][1]);
        u0.y = cvtpk_bf16(pp[0][2], pp[0][3]);
        u0.z = cvtpk_bf16(pp[1][0], pp[1][1]);
        u0.w = cvtpk_bf16(pp[1][2], pp[1][3]);
        u1.x = cvtpk_bf16(pp[2][0], pp[2][1]);
        u1.y = cvtpk_bf16(pp[2][2], pp[2][3]);
        u1.z = cvtpk_bf16(pp[3][0], pp[3][1]);
        u1.w = cvtpk_bf16(pp[3][2], pp[3][3]);
        bp[qh][0] = __builtin_bit_cast(bf16x8, u0);
        bp[qh][1] = __builtin_bit_cast(bf16x8, u1);
      }

      // ---- O^T += V^T . P^T (V fragments read once, used by both q-halves)
      __builtin_amdgcn_s_setprio(1);
#pragma unroll
      for (int dt = 0; dt < 4; ++dt) {
        bf16x8 av0 = lds_frag(Vc, dt * 16 + q, g);
        bf16x8 av1 = lds_frag(Vc, dt * 16 + q, 4 + g);
#pragma unroll
        for (int qh = 0; qh < 2; ++qh) {
          accO[qh][dt] = mfma16(av0, bp[qh][0], accO[qh][dt]);
          accO[qh][dt] = mfma16(av1, bp[qh][1], accO[qh][dt]);
        }
      }
      __builtin_amdgcn_s_setprio(0);
    }

    __syncthreads();  // drains prefetch DMAs; frees this iteration's slots
  }
#undef STAGE

  // group-local full row sums
#pragma unroll
  for (int qh = 0; qh < 2; ++qh) {
    lsum[qh] += __shfl_xor(lsum[qh], 16);
    lsum[qh] += __shfl_xor(lsum[qh], 32);
  }

  // ---- in-block parity merge via LDS scratch (ring is dead) ----
  float* scrO = (float*)Ks;
  float* scrL = (float*)Vs;
  const int si = (w4 * 64 + lane) * 2;
  if (p == 1) {
#pragma unroll
    for (int qh = 0; qh < 2; ++qh) {
      float* so = scrO + (si + qh) * 16;
#pragma unroll
      for (int dt = 0; dt < 4; ++dt) *(float4*)(so + dt * 4) = *(float4*)&accO[qh][dt];
      scrL[si + qh] = lsum[qh];
    }
  }
  __syncthreads();
  if (p == 0) {
    // write UNNORMALIZED partials -- O as bf16 (packed), l as f32
    const int jobj = (b << 5) + i;  // 0..511
    unsigned short* PO_ = PO + ((size_t)(jobj * 2 + h)) * 8192;
    float* PL_ = PL + (jobj * 2 + h) * 128;
#pragma unroll
    for (int qh = 0; qh < 2; ++qh) {
      const float* so = scrO + (si + qh) * 16;
      const float lt = lsum[qh] + scrL[si + qh];
      const int row = w4 * 32 + qh * 16 + q;
      if (g == 0) PL_[row] = lt;
#pragma unroll
      for (int dt = 0; dt < 4; ++dt) {
        float4 ob = *(const float4*)(so + dt * 4);
        uint2 pv;
        pv.x = cvtpk_bf16(accO[qh][dt][0] + ob.x, accO[qh][dt][1] + ob.y);
        pv.y = cvtpk_bf16(accO[qh][dt][2] + ob.z, accO[qh][dt][3] + ob.w);
        *(uint2*)(PO_ + row * 64 + dt * 16 + g * 4) = pv;
      }
    }
  }
}

// ---------------------------------------------------------------------------
// k_red: merge split-K partials. O = (O0 + O1) / (l0 + l1).
// 32 B per thread (uint4 per half, 2x float4 out).
// 512 jobs x 128 rows x 8 d-octs = 524288 threads -> 2048 blocks.
// ---------------------------------------------------------------------------
__global__ __launch_bounds__(256) void k_red(const unsigned short* __restrict__ PO,
                                             const float* __restrict__ PL,
                                             float* __restrict__ out) {
  const int idx = blockIdx.x * 256 + threadIdx.x;
  const int dv = idx & 7;            // 8-elem d-oct
  const int row = (idx >> 3) & 127;
  const int j = idx >> 10;           // 0..511 = b*32 + i
  const int b = j >> 5, i = j & 31;

  const unsigned short* a0 = PO + ((size_t)(j * 2)) * 8192 + row * 64 + dv * 8;
  const uint4 u0 = *(const uint4*)a0;
  const uint4 u1 = *(const uint4*)(a0 + 8192);
  const float rl = 1.0f / (PL[(j * 2) * 128 + row] + PL[(j * 2 + 1) * 128 + row]);

  float* op = out + ((size_t)(b * 4096 + i * 128 + row)) * 64 + dv * 8;
  float4 o0, o1;
  o0.x = (bf2f(u0.x & 0xffffu) + bf2f(u1.x & 0xffffu)) * rl;
  o0.y = (bf2f(u0.x >> 16) + bf2f(u1.x >> 16)) * rl;
  o0.z = (bf2f(u0.y & 0xffffu) + bf2f(u1.y & 0xffffu)) * rl;
  o0.w = (bf2f(u0.y >> 16) + bf2f(u1.y >> 16)) * rl;
  o1.x = (bf2f(u0.z & 0xffffu) + bf2f(u1.z & 0xffffu)) * rl;
  o1.y = (bf2f(u0.z >> 16) + bf2f(u1.z >> 16)) * rl;
  o1.z = (bf2f(u0.w & 0xffffu) + bf2f(u1.w & 0xffffu)) * rl;
  o1.w = (bf2f(u0.w >> 16) + bf2f(u1.w >> 16)) * rl;
  *(float4*)op = o0;
  *(float4*)(op + 4) = o1;
}

// ---------------------------------------------------------------------------
extern "C" void kernel_launch(void* const* d_in, const int* in_sizes, int n_in,
                              void* d_out, int out_size, void* d_ws, size_t ws_size,
                              hipStream_t stream) {
  const float* x  = (const float*)d_in[0];
  const float* Wk = (const float*)d_in[1];
  const float* Wq = (const float*)d_in[2];
  const float* Wv = (const float*)d_in[3];
  float* out = (float*)d_out;

  // workspace (ushorts): WT 73728 | Y 8388608 | VT 4194304 | PO 8388608 |
  // PL 131072 f32 (262144 ushort-equiv). Total ~42.6 MB.
  unsigned short* WT = (unsigned short*)d_ws;
  unsigned short* Y  = WT + 73728;
  unsigned short* VT = Y + 8388608;
  unsigned short* PO = VT + 4194304;
  float*          PL = (float*)(PO + 8388608);

  hipLaunchKernelGGL(k_pack, dim3(288), dim3(256), 0, stream, Wk, Wq, Wv, WT);
  hipLaunchKernelGGL(k_proj, dim3(1024), dim3(256), 0, stream, x, WT, Y, VT);
  hipLaunchKernelGGL(k_attn, dim3(1024), dim3(512), 0, stream, Y, VT, PO, PL);
  hipLaunchKernelGGL(k_red, dim3(2048), dim3(256), 0, stream, PO, PL, out);
}